// Round 1
// baseline (516.001 us; speedup 1.0000x reference)
//
#include <hip/hip_runtime.h>
#include <hip/hip_bf16.h>

// Problem constants
#define BQ 8
#define NP 1025
#define NH 8
#define HD 64
#define ED 512
#define NTOK (BQ * NP)      // 8200 tokens
#define VT_STRIDE 1088      // padded key-stride for V^T (16B-aligned)
#define LDP 72              // K/V/P LDS row stride in shorts (144 B)
#define BLD 68              // bias LDS row stride in floats (2-way banks = free)
#define MS 1088             // maskb row stride (bytes)
#define NEGBIG -3.0e38f

typedef __attribute__((ext_vector_type(8))) short short8;   // 8 bf16 (MFMA A/B frag)
typedef __attribute__((ext_vector_type(4))) float floatx4;  // MFMA C/D frag

static __device__ __forceinline__ unsigned short f2bf_raw(float f) {
    __hip_bfloat16 h = __float2bfloat16(f);
    return *reinterpret_cast<unsigned short*>(&h);
}

// ---------------------------------------------------------------------------
// Kernel 0: fp32 -> bf16 convert (x, W's) + byte-mask precompute.
// maskb[b][q][k], q,k in [0,1088): 1 = attend. q==0||k==0 -> 1 (graph token),
// k>1024 or q>1024 -> 0, else pad_mask[b][q-1][k-1].
// ---------------------------------------------------------------------------
__global__ __launch_bounds__(256) void cvt_kernel(
    const float* __restrict__ x,
    const float* __restrict__ Wq, const float* __restrict__ Wk,
    const float* __restrict__ Wv, const float* __restrict__ Wo,
    const int* __restrict__ pad,
    unsigned short* __restrict__ xbf, unsigned short* __restrict__ wbf,
    unsigned char* __restrict__ maskb)
{
    const int X4 = (NTOK * ED) / 4;       // 1,049,600
    const int W4 = (512 * 512) / 4;       // 65,536
    const int M4 = BQ * MS * (MS / 4);    // 2,367,488
    const int total = X4 + 4 * W4 + M4;
    for (int i = blockIdx.x * 256 + threadIdx.x; i < total; i += gridDim.x * 256) {
        if (i < X4 + 4 * W4) {
            float4 v; ushort4* dstp;
            if (i < X4) {
                v = ((const float4*)x)[i];
                dstp = ((ushort4*)xbf) + i;
            } else {
                int j = i - X4;
                int sel = j >> 16, lo = j & 65535;
                const float4* s = (const float4*)((sel == 0) ? Wq : (sel == 1) ? Wk
                                               : (sel == 2) ? Wv : Wo);
                v = s[lo];
                dstp = ((ushort4*)wbf) + j;
            }
            ushort4 o;
            o.x = f2bf_raw(v.x); o.y = f2bf_raw(v.y);
            o.z = f2bf_raw(v.z); o.w = f2bf_raw(v.w);
            *dstp = o;
        } else {
            int j = i - X4 - 4 * W4;          // [0, M4)
            int b = j / (MS * (MS / 4));
            int rr = j - b * (MS * (MS / 4));
            int q = rr / (MS / 4);
            int c0 = (rr - q * (MS / 4)) * 4;
            unsigned int outw = 0;
            if (q <= 1024) {
#pragma unroll
                for (int e = 0; e < 4; e++) {
                    int c = c0 + e;
                    unsigned v;
                    if (c > 1024) v = 0;
                    else if (q == 0 || c == 0) v = 1;
                    else v = pad[((size_t)b << 20) + ((size_t)(q - 1) << 10) + (c - 1)] ? 1u : 0u;
                    outw |= v << (8 * e);
                }
            }
            *(unsigned int*)(maskb + ((size_t)b * MS + q) * MS + c0) = outw;
        }
    }
}

// ---------------------------------------------------------------------------
// Kernel 1: fused QKV projection, per-b tiling (grid.x = 8*17).
// Outputs: Q,K [bh][np][64] bf16; V^T [bh][d][VT_STRIDE] bf16 via LDS
// transpose (coalesced 16B global stores, np-aligned).
// ---------------------------------------------------------------------------
__global__ __launch_bounds__(256) void qkv_gemm_kernel(
    const unsigned short* __restrict__ xbf,   // [NTOK,512] bf16
    const unsigned short* __restrict__ wbf,   // [1536,512] bf16 (Wq,Wk,Wv rows)
    const float* __restrict__ bq, const float* __restrict__ bk,
    const float* __restrict__ bv,
    __hip_bfloat16* __restrict__ qws, __hip_bfloat16* __restrict__ kws,
    __hip_bfloat16* __restrict__ vtws)
{
    __shared__ __align__(16) unsigned short As[64 * 32];
    __shared__ __align__(16) unsigned short Bs[64 * 32];
    __shared__ __align__(16) unsigned short Ts[64 * LDP];  // V transpose staging

    const int t = threadIdx.x;
    const int wave = t >> 6, lane = t & 63;
    const int quad = lane >> 4, l16 = lane & 15;
    const int bidx = blockIdx.x;              // 0..135
    const int bb = bidx / 17;
    const int m0 = (bidx % 17) * 64;          // np base
    const int ng0 = blockIdx.y * 64;          // [0,1536)
    const int wsel = ng0 >> 9;
    const int n0 = ng0 & 511;

    const int arow = t >> 2, aseg = (t & 3) * 8;
    const int np_a = min(m0 + arow, NP - 1);
    const unsigned short* aptr = xbf + ((size_t)bb * NP + np_a) * ED + aseg;
    const unsigned short* bptr = wbf + (size_t)(ng0 + arow) * ED + aseg;

    floatx4 acc[4];
#pragma unroll
    for (int i = 0; i < 4; i++) acc[i] = (floatx4){0.f, 0.f, 0.f, 0.f};

    uint4 ar = *(const uint4*)aptr;
    uint4 br = *(const uint4*)bptr;
    for (int s = 0; s < 16; s++) {
        __syncthreads();
        *(uint4*)&As[arow * 32 + aseg] = ar;
        *(uint4*)&Bs[arow * 32 + aseg] = br;
        if (s < 15) {
            ar = *(const uint4*)(aptr + (s + 1) * 32);
            br = *(const uint4*)(bptr + (s + 1) * 32);
        }
        __syncthreads();
        short8 a = *(const short8*)&As[(16 * wave + l16) * 32 + quad * 8];
#pragma unroll
        for (int nt = 0; nt < 4; nt++) {
            short8 bfr = *(const short8*)&Bs[(nt * 16 + l16) * 32 + quad * 8];
            acc[nt] = __builtin_amdgcn_mfma_f32_16x16x32_bf16(a, bfr, acc[nt], 0, 0, 0);
        }
    }

    if (wsel < 2) {
        const float* bias = (wsel == 0) ? bq : bk;
        __hip_bfloat16* dst = (wsel == 0) ? qws : kws;
#pragma unroll
        for (int nt = 0; nt < 4; nt++) {
            int lcol = n0 + nt * 16 + l16;
            float bvv = bias[lcol];
            int hh = lcol >> 6, d = lcol & 63;
            int bh = bb * NH + hh;
#pragma unroll
            for (int r = 0; r < 4; r++) {
                int np = m0 + 16 * wave + quad * 4 + r;
                if (np >= NP) continue;
                dst[((size_t)bh * NP + np) * HD + d] = __float2bfloat16(acc[nt][r] + bvv);
            }
        }
    } else {
        // V: write to LDS transposed, then coalesced global store
#pragma unroll
        for (int nt = 0; nt < 4; nt++) {
            int d = nt * 16 + l16;
            float bvv = bv[n0 + nt * 16 + l16];
#pragma unroll
            for (int r = 0; r < 4; r++) {
                int nploc = 16 * wave + quad * 4 + r;
                Ts[d * LDP + nploc] = f2bf_raw(acc[nt][r] + bvv);
            }
        }
        __syncthreads();
        const int hh = n0 >> 6;
        const size_t vrowbase = (size_t)(bb * NH + hh) * HD;
#pragma unroll
        for (int i = 0; i < 2; i++) {
            int idx = t + 256 * i;
            int d = idx >> 3, seg = idx & 7;
            int npb = m0 + seg * 8;
            __hip_bfloat16* dst = vtws + (vrowbase + d) * VT_STRIDE + npb;
            if (npb + 7 <= NP - 1) {
                *(uint4*)(void*)dst = *(uint4*)&Ts[d * LDP + seg * 8];
            } else {
#pragma unroll
                for (int e = 0; e < 8; e++) {
                    int np = npb + e;
                    if (np < NP) dst[e] = *(__hip_bfloat16*)&Ts[d * LDP + seg * 8 + e];
                }
            }
        }
    }
}

// ---------------------------------------------------------------------------
// Kernel 2: flash attention.  Per iter: 9 wide loads/thread (K/V 4, bias 4,
// mask 1), mask folded into fp32 bias in regs, staged to LDS in the barrier
// window.  Per-lane deferred l-reduction.
// ---------------------------------------------------------------------------
#define LOAD_BIAS(k0v, bmv) do {                                              \
    uint4 mu = *(const uint4*)(mrow + (k0v) + bc0);                           \
    _Pragma("unroll") for (int sgi = 0; sgi < 4; sgi++) {                     \
        int c = (k0v) + bc0 + sgi * 4;                                        \
        float4 f;                                                             \
        if (c + 3 <= NP - 1) f = *(const float4*)(brow + c);                  \
        else if (c == NP - 1) { f.x = brow[NP - 1]; f.y = f.z = f.w = 0.f; }  \
        else { f.x = f.y = f.z = f.w = 0.f; }                                 \
        unsigned mw = ((const unsigned*)&mu)[sgi];                            \
        bmv[sgi * 4 + 0] = (mw & 0xffu)       ? f.x : NEGBIG;                 \
        bmv[sgi * 4 + 1] = (mw & 0xff00u)     ? f.y : NEGBIG;                 \
        bmv[sgi * 4 + 2] = (mw & 0xff0000u)   ? f.z : NEGBIG;                 \
        bmv[sgi * 4 + 3] = (mw & 0xff000000u) ? f.w : NEGBIG;                 \
    } } while (0)

__global__ __launch_bounds__(256, 3) void attn_kernel(
    const __hip_bfloat16* __restrict__ qws,
    const __hip_bfloat16* __restrict__ kws,
    const __hip_bfloat16* __restrict__ vtws,
    const float* __restrict__ attn_bias,           // [B,H,NP,NP] fp32
    const unsigned char* __restrict__ maskb,       // [B,1088,1088] bytes
    __hip_bfloat16* __restrict__ attnout)          // [B,NP,512] bf16 (ws)
{
    __shared__ __align__(16) unsigned short Ks[64 * LDP];
    __shared__ __align__(16) unsigned short Vs[64 * LDP];
    __shared__ __align__(16) unsigned short Ps[64 * LDP];
    __shared__ __align__(16) float Bf[64 * BLD];

    const int t = threadIdx.x;
    const int wave = t >> 6, lane = t & 63;
    const int quad = lane >> 4, l16 = lane & 15;
    const int q0 = blockIdx.x * 64;
    const int bh = blockIdx.y;
    const int b = bh >> 3, h = bh & 7;

    // K/V staging coords
    const int r0 = t >> 3, r1 = 32 + (t >> 3);
    const int sg = (t & 7) * 8;
    const unsigned short* kbase = (const unsigned short*)kws + (size_t)bh * NP * HD;
    const unsigned short* vbase = (const unsigned short*)vtws + (size_t)bh * HD * VT_STRIDE;

    // bias staging coords: row br, 64 cols per 4 threads
    const int br = t >> 2, bc0 = (t & 3) * 16;
    const int qrow_g = min(q0 + br, NP - 1);
    const float* brow = attn_bias + ((size_t)bh * NP + qrow_g) * NP;
    const unsigned char* mrow = maskb + ((size_t)b * MS + qrow_g) * MS;

    // Q fragments in registers
    const int qrow = min(q0 + 16 * wave + l16, NP - 1);
    const unsigned short* qb = (const unsigned short*)qws + ((size_t)bh * NP + qrow) * HD;
    short8 qf0 = *(const short8*)(qb + quad * 8);
    short8 qf1 = *(const short8*)(qb + 32 + quad * 8);

    int qrl[4];
#pragma unroll
    for (int r = 0; r < 4; r++) qrl[r] = 16 * wave + quad * 4 + r;

    // preload tile 0
    {
        int gk0 = min(r0, NP - 1), gk1 = min(r1, NP - 1);
        *(uint4*)&Ks[r0 * LDP + sg] = *(const uint4*)(kbase + (size_t)gk0 * HD + sg);
        *(uint4*)&Ks[r1 * LDP + sg] = *(const uint4*)(kbase + (size_t)gk1 * HD + sg);
        *(uint4*)&Vs[r0 * LDP + sg] = *(const uint4*)(vbase + (size_t)r0 * VT_STRIDE + sg);
        *(uint4*)&Vs[r1 * LDP + sg] = *(const uint4*)(vbase + (size_t)r1 * VT_STRIDE + sg);
        float bm0[16];
        LOAD_BIAS(0, bm0);
#pragma unroll
        for (int sgi = 0; sgi < 4; sgi++)
            *(float4*)&Bf[br * BLD + bc0 + sgi * 4] = *(float4*)&bm0[sgi * 4];
    }
    __syncthreads();

    float m_run[4], l_lane[4];
    floatx4 o_acc[4];
#pragma unroll
    for (int r = 0; r < 4; r++) { m_run[r] = NEGBIG; l_lane[r] = 0.f; }
#pragma unroll
    for (int nt = 0; nt < 4; nt++) o_acc[nt] = (floatx4){0.f, 0.f, 0.f, 0.f};

    for (int kt = 0; kt < 17; kt++) {
        const int k0 = kt * 64;
        const bool nxt = (kt < 16);

        // ---- prefetch next K/V + masked bias into regs ----
        uint4 kr0, kr1, vr0, vr1;
        float bm[16];
        if (nxt) {
            const int k0n = k0 + 64;
            int gk0 = min(k0n + r0, NP - 1), gk1 = min(k0n + r1, NP - 1);
            kr0 = *(const uint4*)(kbase + (size_t)gk0 * HD + sg);
            kr1 = *(const uint4*)(kbase + (size_t)gk1 * HD + sg);
            vr0 = *(const uint4*)(vbase + (size_t)r0 * VT_STRIDE + k0n + sg);
            vr1 = *(const uint4*)(vbase + (size_t)r1 * VT_STRIDE + k0n + sg);
            LOAD_BIAS(k0n, bm);
        }

        // ---- S = Q K^T ----
        floatx4 s4[4];
#pragma unroll
        for (int nt = 0; nt < 4; nt++) s4[nt] = (floatx4){0.f, 0.f, 0.f, 0.f};
#pragma unroll
        for (int kc = 0; kc < 2; kc++) {
            short8 a = kc ? qf1 : qf0;
#pragma unroll
            for (int nt = 0; nt < 4; nt++) {
                short8 bbf = *(const short8*)&Ks[(nt * 16 + l16) * LDP + kc * 32 + quad * 8];
                s4[nt] = __builtin_amdgcn_mfma_f32_16x16x32_bf16(a, bbf, s4[nt], 0, 0, 0);
            }
        }

        // ---- scale + bias (LDS) ; row max ----
        float mx[4] = {NEGBIG, NEGBIG, NEGBIG, NEGBIG};
#pragma unroll
        for (int nt = 0; nt < 4; nt++) {
#pragma unroll
            for (int r = 0; r < 4; r++) {
                float sv = fmaf(s4[nt][r], 0.125f, Bf[qrl[r] * BLD + nt * 16 + l16]);
                s4[nt][r] = sv;
                mx[r] = fmaxf(mx[r], sv);
            }
        }
#pragma unroll
        for (int r = 0; r < 4; r++) {
            mx[r] = fmaxf(mx[r], __shfl_xor(mx[r], 1));
            mx[r] = fmaxf(mx[r], __shfl_xor(mx[r], 2));
            mx[r] = fmaxf(mx[r], __shfl_xor(mx[r], 4));
            mx[r] = fmaxf(mx[r], __shfl_xor(mx[r], 8));
        }
        float m_new[4], alpha[4], rs[4];
#pragma unroll
        for (int r = 0; r < 4; r++) {
            m_new[r] = fmaxf(m_run[r], mx[r]);
            alpha[r] = __expf(m_run[r] - m_new[r]);
            rs[r] = 0.f;
        }
#pragma unroll
        for (int nt = 0; nt < 4; nt++) {
#pragma unroll
            for (int r = 0; r < 4; r++) {
                float p = __expf(s4[nt][r] - m_new[r]);   // masked -> 0
                rs[r] += p;
                Ps[qrl[r] * LDP + nt * 16 + l16] = f2bf_raw(p);
            }
        }
#pragma unroll
        for (int r = 0; r < 4; r++) {
            l_lane[r] = l_lane[r] * alpha[r] + rs[r];     // per-lane partial
            m_run[r] = m_new[r];
        }
#pragma unroll
        for (int nt = 0; nt < 4; nt++)
#pragma unroll
            for (int r = 0; r < 4; r++) o_acc[nt][r] *= alpha[r];

        // ---- O += P V  (same-wave Ps write->read; per-wave DS order) ----
#pragma unroll
        for (int kc = 0; kc < 2; kc++) {
            short8 a = *(const short8*)&Ps[(16 * wave + l16) * LDP + kc * 32 + quad * 8];
#pragma unroll
            for (int nt = 0; nt < 4; nt++) {
                short8 bbf = *(const short8*)&Vs[(nt * 16 + l16) * LDP + kc * 32 + quad * 8];
                o_acc[nt] = __builtin_amdgcn_mfma_f32_16x16x32_bf16(a, bbf, o_acc[nt], 0, 0, 0);
            }
        }

        // ---- stage prefetched tiles into LDS ----
        __syncthreads();
        if (nxt) {
            *(uint4*)&Ks[r0 * LDP + sg] = kr0;
            *(uint4*)&Ks[r1 * LDP + sg] = kr1;
            *(uint4*)&Vs[r0 * LDP + sg] = vr0;
            *(uint4*)&Vs[r1 * LDP + sg] = vr1;
#pragma unroll
            for (int sgi = 0; sgi < 4; sgi++)
                *(float4*)&Bf[br * BLD + bc0 + sgi * 4] = *(float4*)&bm[sgi * 4];
        }
        __syncthreads();
    }

    // epilogue: reduce l across the 16-lane row group, normalize, store
#pragma unroll
    for (int r = 0; r < 4; r++) {
        float lt = l_lane[r];
        lt += __shfl_xor(lt, 1);
        lt += __shfl_xor(lt, 2);
        lt += __shfl_xor(lt, 4);
        lt += __shfl_xor(lt, 8);
        int q = q0 + qrl[r];
        if (q >= NP) continue;
        float inv = 1.f / lt;
#pragma unroll
        for (int nt = 0; nt < 4; nt++) {
            attnout[((size_t)b * NP + q) * ED + h * 64 + nt * 16 + l16] =
                __float2bfloat16(o_acc[nt][r] * inv);
        }
    }
}

// ---------------------------------------------------------------------------
// Kernel 3: output projection  out = attnout @ Wo^T + bo  (fp32 out)
// ---------------------------------------------------------------------------
__global__ __launch_bounds__(256) void proj_gemm_kernel(
    const unsigned short* __restrict__ A,     // [8200,512] bf16 ws
    const unsigned short* __restrict__ wobf,  // [512,512] bf16
    const float* __restrict__ bo,
    float* __restrict__ out)
{
    __shared__ __align__(16) unsigned short As[64 * 32];
    __shared__ __align__(16) unsigned short Bs[64 * 32];

    const int t = threadIdx.x;
    const int wave = t >> 6, lane = t & 63;
    const int quad = lane >> 4, l16 = lane & 15;
    const int m0 = blockIdx.x * 64;
    const int n0 = blockIdx.y * 64;

    const int arow = t >> 2, aseg = (t & 3) * 8;
    const int ga = min(m0 + arow, NTOK - 1);
    const unsigned short* aptr = A + (size_t)ga * 512 + aseg;
    const unsigned short* bptr = wobf + (size_t)(n0 + arow) * 512 + aseg;

    floatx4 acc[4];
#pragma unroll
    for (int i = 0; i < 4; i++) acc[i] = (floatx4){0.f, 0.f, 0.f, 0.f};

    uint4 ar = *(const uint4*)aptr;
    uint4 br = *(const uint4*)bptr;
    for (int s = 0; s < 16; s++) {
        __syncthreads();
        *(uint4*)&As[arow * 32 + aseg] = ar;
        *(uint4*)&Bs[arow * 32 + aseg] = br;
        if (s < 15) {
            ar = *(const uint4*)(aptr + (s + 1) * 32);
            br = *(const uint4*)(bptr + (s + 1) * 32);
        }
        __syncthreads();
        short8 a = *(const short8*)&As[(16 * wave + l16) * 32 + quad * 8];
#pragma unroll
        for (int nt = 0; nt < 4; nt++) {
            short8 bfr = *(const short8*)&Bs[(nt * 16 + l16) * 32 + quad * 8];
            acc[nt] = __builtin_amdgcn_mfma_f32_16x16x32_bf16(a, bfr, acc[nt], 0, 0, 0);
        }
    }

#pragma unroll
    for (int nt = 0; nt < 4; nt++) {
        int col = n0 + nt * 16 + l16;
        float bvv = bo[col];
#pragma unroll
        for (int r = 0; r < 4; r++) {
            int m = m0 + 16 * wave + quad * 4 + r;
            if (m >= NTOK) continue;
            out[(size_t)m * ED + col] = acc[nt][r] + bvv;
        }
    }
}

// ---------------------------------------------------------------------------
extern "C" void kernel_launch(void* const* d_in, const int* in_sizes, int n_in,
                              void* d_out, int out_size, void* d_ws, size_t ws_size,
                              hipStream_t stream) {
    (void)in_sizes; (void)n_in; (void)out_size; (void)ws_size;
    const float* x         = (const float*)d_in[0];
    const float* attn_bias = (const float*)d_in[1];
    const int*   pad_mask  = (const int*)d_in[2];
    const float* Wq = (const float*)d_in[3];
    const float* bq = (const float*)d_in[4];
    const float* Wk = (const float*)d_in[5];
    const float* bk = (const float*)d_in[6];
    const float* Wv = (const float*)d_in[7];
    const float* bv = (const float*)d_in[8];
    const float* Wo = (const float*)d_in[9];
    const float* bo = (const float*)d_in[10];
    float* out = (float*)d_out;

    // workspace layout (bytes); attnout reuses xbf (dead after qkv)
    char* ws = (char*)d_ws;
    const size_t XBF_BYTES = (size_t)NTOK * ED * 2;               // 8,396,800
    const size_t WBF_BYTES = (size_t)2048 * 512 * 2;              // 2,097,152
    const size_t QK_BYTES  = (size_t)BQ * NH * NP * HD * 2;       // 8,396,800
    const size_t VT_BYTES  = (size_t)BQ * NH * HD * VT_STRIDE * 2;// 8,912,896
    unsigned short* xbf    = (unsigned short*)(ws);
    unsigned short* wbf    = (unsigned short*)(ws + XBF_BYTES);
    __hip_bfloat16* qws    = (__hip_bfloat16*)(ws + XBF_BYTES + WBF_BYTES);
    __hip_bfloat16* kws    = (__hip_bfloat16*)(ws + XBF_BYTES + WBF_BYTES + QK_BYTES);
    __hip_bfloat16* vtws   = (__hip_bfloat16*)(ws + XBF_BYTES + WBF_BYTES + 2 * QK_BYTES);
    unsigned char*  maskb  = (unsigned char*)(ws + XBF_BYTES + WBF_BYTES + 2 * QK_BYTES + VT_BYTES);
    __hip_bfloat16* attnout = (__hip_bfloat16*)xbf;   // reuse

    cvt_kernel<<<4096, 256, 0, stream>>>(x, Wq, Wk, Wv, Wo, pad_mask, xbf, wbf, maskb);
    qkv_gemm_kernel<<<dim3(136, 24), 256, 0, stream>>>(
        xbf, wbf, bq, bk, bv, qws, kws, vtws);
    attn_kernel<<<dim3(17, 64), 256, 0, stream>>>(
        qws, kws, vtws, attn_bias, maskb, attnout);
    proj_gemm_kernel<<<dim3(129, 8), 256, 0, stream>>>(
        (const unsigned short*)attnout, wbf + (size_t)1536 * 512, bo, out);
}

// Round 2
// 509.837 us; speedup vs baseline: 1.0121x; 1.0121x over previous
//
#include <hip/hip_runtime.h>
#include <hip/hip_bf16.h>

// Problem constants
#define BQ 8
#define NP 1025
#define NH 8
#define HD 64
#define ED 512
#define NTOK (BQ * NP)      // 8200 tokens
#define VT_STRIDE 1088      // padded key-stride for V^T (16B-aligned)
#define LDP 72              // K/V/P LDS row stride in shorts (144 B) - conflict-free
#define LDA 40              // GEMM As/Bs row stride in shorts (80 B = 20 banks, 2-way free)
#define MROW 256            // maskbits row stride (bytes)
#define NEGBIG -3.0e38f

typedef __attribute__((ext_vector_type(8))) short short8;   // 8 bf16 (MFMA A/B frag)
typedef __attribute__((ext_vector_type(4))) float floatx4;  // MFMA C/D frag

static __device__ __forceinline__ unsigned short f2bf_raw(float f) {
    __hip_bfloat16 h = __float2bfloat16(f);
    return *reinterpret_cast<unsigned short*>(&h);
}

// ---------------------------------------------------------------------------
// Kernel 0: fp32 -> bf16 convert (x, W's) + BIT-mask precompute via ballot.
// maskbits[b][q][k/8] bit k: 1 = attend. q,k in [0,1088).
// q>1024||k>1024 -> 0; q==0||k==0 -> 1; else pad_mask[b][q-1][k-1].
// Row stride MROW=256 B; only first 136 B of each row are written/read.
// ---------------------------------------------------------------------------
__global__ __launch_bounds__(256) void cvt_kernel(
    const float* __restrict__ x,
    const float* __restrict__ Wq, const float* __restrict__ Wk,
    const float* __restrict__ Wv, const float* __restrict__ Wo,
    const int* __restrict__ pad,
    unsigned short* __restrict__ xbf, unsigned short* __restrict__ wbf,
    unsigned char* __restrict__ maskbits)
{
    const int X4 = (NTOK * ED) / 4;       // 1,049,600
    const int W4 = (512 * 512) / 4;       // 65,536
    const int ELEM = X4 + 4 * W4;         // 1,311,744 (multiple of 64)
    const int MWAVES = BQ * 1088 * 17;    // 147,968 ballot words
    const int total = ELEM + MWAVES * 64;
    for (int i = blockIdx.x * 256 + threadIdx.x; i < total; i += gridDim.x * 256) {
        if (i < ELEM) {
            float4 v; ushort4* dstp;
            if (i < X4) {
                v = ((const float4*)x)[i];
                dstp = ((ushort4*)xbf) + i;
            } else {
                int j = i - X4;
                int sel = j >> 16, lo = j & 65535;
                const float4* s = (const float4*)((sel == 0) ? Wq : (sel == 1) ? Wk
                                               : (sel == 2) ? Wv : Wo);
                v = s[lo];
                dstp = ((ushort4*)wbf) + j;
            }
            ushort4 o;
            o.x = f2bf_raw(v.x); o.y = f2bf_raw(v.y);
            o.z = f2bf_raw(v.z); o.w = f2bf_raw(v.w);
            *dstp = o;
        } else {
            int j = i - ELEM;                 // lane-slot in mask space
            int w = j >> 6, ln = j & 63;
            int b = w / (1088 * 17);
            int rr = w - b * (1088 * 17);
            int q = rr / 17, kc = rr - q * 17;
            int k = kc * 64 + ln;
            bool bit;
            if (q > 1024 || k > 1024) bit = false;
            else if (q == 0 || k == 0) bit = true;
            else bit = pad[((size_t)b << 20) + ((size_t)(q - 1) << 10) + (k - 1)] != 0;
            unsigned long long bal = __ballot(bit);
            if (ln == 0)
                *(unsigned long long*)(maskbits + ((size_t)(b * 1088 + q)) * MROW + kc * 8) = bal;
        }
    }
}

// ---------------------------------------------------------------------------
// Kernel 1: fused QKV projection, 64x128 tiles (grid 136 x 12).
// by>>2 selects Q/K/V; each block covers 128 output cols = 2 heads.
// Outputs: Q,K [bh][np][64] bf16; V^T [bh][d][VT_STRIDE] bf16 via LDS
// transpose (two 64-col passes).
// ---------------------------------------------------------------------------
__global__ __launch_bounds__(256) void qkv_gemm_kernel(
    const unsigned short* __restrict__ xbf,   // [NTOK,512] bf16
    const unsigned short* __restrict__ wbf,   // [1536,512] bf16 (Wq,Wk,Wv rows)
    const float* __restrict__ bq, const float* __restrict__ bk,
    const float* __restrict__ bv,
    __hip_bfloat16* __restrict__ qws, __hip_bfloat16* __restrict__ kws,
    __hip_bfloat16* __restrict__ vtws)
{
    __shared__ __align__(16) unsigned short As[64 * LDA];
    __shared__ __align__(16) unsigned short Bs[128 * LDA];
    __shared__ __align__(16) unsigned short Ts[64 * LDP];  // V transpose staging

    const int t = threadIdx.x;
    const int wave = t >> 6, lane = t & 63;
    const int quad = lane >> 4, l16 = lane & 15;
    const int bidx = blockIdx.x;              // 0..135
    const int bb = bidx / 17;
    const int m0 = (bidx % 17) * 64;          // np base
    const int by = blockIdx.y;                // 0..11
    const int ng0 = by * 128;                 // [0,1536)
    const int wsel = by >> 2;                 // 0:Q 1:K 2:V
    const int n0 = (by & 3) * 128;            // within 512

    const int arow = t >> 2, aseg = (t & 3) * 8;
    const int np_a = min(m0 + arow, NP - 1);
    const unsigned short* aptr = xbf + ((size_t)bb * NP + np_a) * ED + aseg;
    const int brw = t >> 1, bseg = (t & 1) * 16;
    const unsigned short* bptr = wbf + (size_t)(ng0 + brw) * ED + bseg;

    floatx4 acc[8];
#pragma unroll
    for (int i = 0; i < 8; i++) acc[i] = (floatx4){0.f, 0.f, 0.f, 0.f};

    uint4 ar = *(const uint4*)aptr;
    uint4 br0 = *(const uint4*)bptr;
    uint4 br1 = *(const uint4*)(bptr + 8);
    for (int s = 0; s < 16; s++) {
        __syncthreads();
        *(uint4*)&As[arow * LDA + aseg] = ar;
        *(uint4*)&Bs[brw * LDA + bseg] = br0;
        *(uint4*)&Bs[brw * LDA + bseg + 8] = br1;
        if (s < 15) {
            ar = *(const uint4*)(aptr + (s + 1) * 32);
            br0 = *(const uint4*)(bptr + (s + 1) * 32);
            br1 = *(const uint4*)(bptr + (s + 1) * 32 + 8);
        }
        __syncthreads();
        short8 a = *(const short8*)&As[(16 * wave + l16) * LDA + quad * 8];
#pragma unroll
        for (int nt = 0; nt < 8; nt++) {
            short8 bfr = *(const short8*)&Bs[(nt * 16 + l16) * LDA + quad * 8];
            acc[nt] = __builtin_amdgcn_mfma_f32_16x16x32_bf16(a, bfr, acc[nt], 0, 0, 0);
        }
    }

    if (wsel < 2) {
        const float* bias = (wsel == 0) ? bq : bk;
        __hip_bfloat16* dst = (wsel == 0) ? qws : kws;
#pragma unroll
        for (int nt = 0; nt < 8; nt++) {
            int lcol = n0 + nt * 16 + l16;
            float bvv = bias[lcol];
            int hh = lcol >> 6, d = lcol & 63;
            int bh = bb * NH + hh;
#pragma unroll
            for (int r = 0; r < 4; r++) {
                int np = m0 + 16 * wave + quad * 4 + r;
                if (np >= NP) continue;
                dst[((size_t)bh * NP + np) * HD + d] = __float2bfloat16(acc[nt][r] + bvv);
            }
        }
    } else {
        // V: two 64-col passes through Ts (LDS transpose), coalesced stores
#pragma unroll
        for (int p = 0; p < 2; p++) {
            if (p) __syncthreads();           // pass-0 reads done before overwrite
#pragma unroll
            for (int ntl = 0; ntl < 4; ntl++) {
                int nt = p * 4 + ntl;
                int d = ntl * 16 + l16;
                float bvv = bv[n0 + nt * 16 + l16];
#pragma unroll
                for (int r = 0; r < 4; r++) {
                    int nploc = 16 * wave + quad * 4 + r;
                    Ts[d * LDP + nploc] = f2bf_raw(acc[nt][r] + bvv);
                }
            }
            __syncthreads();
            const int hh = (n0 + p * 64) >> 6;
            const size_t vrowbase = (size_t)(bb * NH + hh) * HD;
#pragma unroll
            for (int i = 0; i < 2; i++) {
                int idx = t + 256 * i;
                int d = idx >> 3, seg = idx & 7;
                int npb = m0 + seg * 8;
                __hip_bfloat16* dst = vtws + (vrowbase + d) * VT_STRIDE + npb;
                if (npb + 7 <= NP - 1) {
                    *(uint4*)(void*)dst = *(uint4*)&Ts[d * LDP + seg * 8];
                } else {
#pragma unroll
                    for (int e = 0; e < 8; e++) {
                        int np = npb + e;
                        if (np < NP) dst[e] = *(__hip_bfloat16*)&Ts[d * LDP + seg * 8 + e];
                    }
                }
            }
        }
    }
}

// ---------------------------------------------------------------------------
// Kernel 2: flash attention. No bias LDS (consumer-aligned direct fp32 loads,
// prefetched one tile ahead in regs), bit-mask broadcast loads, K/V reg
// prefetch + LDS stage, setprio around MFMA, defer-rescale (THR=8).
// LDS = 27.6 KB -> 4 blocks/CU at launch_bounds(256,4).
// ---------------------------------------------------------------------------
__global__ __launch_bounds__(256, 4) void attn_kernel(
    const __hip_bfloat16* __restrict__ qws,
    const __hip_bfloat16* __restrict__ kws,
    const __hip_bfloat16* __restrict__ vtws,
    const float* __restrict__ attn_bias,           // [B,H,NP,NP] fp32
    const unsigned char* __restrict__ maskbits,    // [B,1088,MROW] bit-packed
    __hip_bfloat16* __restrict__ attnout)          // [B,NP,512] bf16 (ws)
{
    __shared__ __align__(16) unsigned short Ks[64 * LDP];
    __shared__ __align__(16) unsigned short Vs[64 * LDP];
    __shared__ __align__(16) unsigned short Ps[64 * LDP];

    const int t = threadIdx.x;
    const int wave = t >> 6, lane = t & 63;
    const int quad = lane >> 4, l16 = lane & 15;
    const int q0 = blockIdx.x * 64;
    const int bh = blockIdx.y;
    const int b = bh >> 3, h = bh & 7;

    // K/V staging coords
    const int r0 = t >> 3, r1 = 32 + (t >> 3);
    const int sg = (t & 7) * 8;
    const unsigned short* kbase = (const unsigned short*)kws + (size_t)bh * NP * HD;
    const unsigned short* vbase = (const unsigned short*)vtws + (size_t)bh * HD * VT_STRIDE;

    // per-row bias/mask pointers (rows this thread consumes)
    const float* browp[4];
    const unsigned char* mrowp[4];
#pragma unroll
    for (int r = 0; r < 4; r++) {
        int qr = q0 + 16 * wave + quad * 4 + r;          // 0..1087
        browp[r] = attn_bias + ((size_t)bh * NP + min(qr, NP - 1)) * NP;
        mrowp[r] = maskbits + ((size_t)(b * 1088 + qr)) * MROW;
    }

    // Q fragments in registers
    const int qrow = min(q0 + 16 * wave + l16, NP - 1);
    const unsigned short* qb = (const unsigned short*)qws + ((size_t)bh * NP + qrow) * HD;
    short8 qf0 = *(const short8*)(qb + quad * 8);
    short8 qf1 = *(const short8*)(qb + 32 + quad * 8);

    // preload tile 0: K/V to LDS, bias+mask to regs
    {
        int gk0 = min(r0, NP - 1), gk1 = min(r1, NP - 1);
        *(uint4*)&Ks[r0 * LDP + sg] = *(const uint4*)(kbase + (size_t)gk0 * HD + sg);
        *(uint4*)&Ks[r1 * LDP + sg] = *(const uint4*)(kbase + (size_t)gk1 * HD + sg);
        *(uint4*)&Vs[r0 * LDP + sg] = *(const uint4*)(vbase + (size_t)r0 * VT_STRIDE + sg);
        *(uint4*)&Vs[r1 * LDP + sg] = *(const uint4*)(vbase + (size_t)r1 * VT_STRIDE + sg);
    }
    float biasr[16];
    uint2 mr[4];
#pragma unroll
    for (int nt = 0; nt < 4; nt++) {
        int cc = min(nt * 16 + l16, NP - 1);
#pragma unroll
        for (int r = 0; r < 4; r++) biasr[nt * 4 + r] = browp[r][cc];
    }
#pragma unroll
    for (int r = 0; r < 4; r++) mr[r] = *(const uint2*)(mrowp[r]);
    __syncthreads();

    float m_run[4], l_lane[4];
    floatx4 o_acc[4];
#pragma unroll
    for (int r = 0; r < 4; r++) { m_run[r] = NEGBIG; l_lane[r] = 0.f; }
#pragma unroll
    for (int nt = 0; nt < 4; nt++) o_acc[nt] = (floatx4){0.f, 0.f, 0.f, 0.f};

    for (int kt = 0; kt < 17; kt++) {
        const int k0 = kt * 64;
        const bool nxt = (kt < 16);

        // ---- prefetch next K/V tile into regs ----
        uint4 kr0, kr1, vr0, vr1;
        if (nxt) {
            const int k0n = k0 + 64;
            int gk0 = min(k0n + r0, NP - 1), gk1 = min(k0n + r1, NP - 1);
            kr0 = *(const uint4*)(kbase + (size_t)gk0 * HD + sg);
            kr1 = *(const uint4*)(kbase + (size_t)gk1 * HD + sg);
            vr0 = *(const uint4*)(vbase + (size_t)r0 * VT_STRIDE + k0n + sg);
            vr1 = *(const uint4*)(vbase + (size_t)r1 * VT_STRIDE + k0n + sg);
        }

        // ---- S = Q K^T ----
        floatx4 s4[4];
#pragma unroll
        for (int nt = 0; nt < 4; nt++) s4[nt] = (floatx4){0.f, 0.f, 0.f, 0.f};
        __builtin_amdgcn_s_setprio(1);
#pragma unroll
        for (int kc = 0; kc < 2; kc++) {
            short8 a = kc ? qf1 : qf0;
#pragma unroll
            for (int nt = 0; nt < 4; nt++) {
                short8 bbf = *(const short8*)&Ks[(nt * 16 + l16) * LDP + kc * 32 + quad * 8];
                s4[nt] = __builtin_amdgcn_mfma_f32_16x16x32_bf16(a, bbf, s4[nt], 0, 0, 0);
            }
        }
        __builtin_amdgcn_s_setprio(0);

        // ---- scale + bias + mask ; row max ----
        float mx[4] = {NEGBIG, NEGBIG, NEGBIG, NEGBIG};
#pragma unroll
        for (int nt = 0; nt < 4; nt++) {
#pragma unroll
            for (int r = 0; r < 4; r++) {
                unsigned mw = (nt < 2) ? (mr[r].x >> l16) : (mr[r].y >> l16);
                unsigned bit = (mw >> ((nt & 1) * 16)) & 1u;
                float sv = bit ? fmaf(s4[nt][r], 0.125f, biasr[nt * 4 + r]) : NEGBIG;
                s4[nt][r] = sv;
                mx[r] = fmaxf(mx[r], sv);
            }
        }
#pragma unroll
        for (int r = 0; r < 4; r++) {
            mx[r] = fmaxf(mx[r], __shfl_xor(mx[r], 1));
            mx[r] = fmaxf(mx[r], __shfl_xor(mx[r], 2));
            mx[r] = fmaxf(mx[r], __shfl_xor(mx[r], 4));
            mx[r] = fmaxf(mx[r], __shfl_xor(mx[r], 8));
        }
        // ---- defer-rescale: only rescale when max grew by > 8 ----
        float m_new[4];
        bool needs = false;
#pragma unroll
        for (int r = 0; r < 4; r++) {
            m_new[r] = fmaxf(m_run[r], mx[r]);
            needs = needs || (mx[r] > m_run[r] + 8.0f);
        }
        if (__any(needs)) {
#pragma unroll
            for (int r = 0; r < 4; r++) {
                float al = __expf(m_run[r] - m_new[r]);
                l_lane[r] *= al;
                m_run[r] = m_new[r];
#pragma unroll
                for (int nt = 0; nt < 4; nt++) o_acc[nt][r] *= al;
            }
        }
        float rs[4] = {0.f, 0.f, 0.f, 0.f};
#pragma unroll
        for (int nt = 0; nt < 4; nt++) {
#pragma unroll
            for (int r = 0; r < 4; r++) {
                float p = __expf(s4[nt][r] - m_run[r]);   // masked -> 0
                rs[r] += p;
                Ps[(16 * wave + quad * 4 + r) * LDP + nt * 16 + l16] = f2bf_raw(p);
            }
        }
#pragma unroll
        for (int r = 0; r < 4; r++) l_lane[r] += rs[r];

        // ---- issue next tile's bias+mask loads (consumed next iter) ----
        if (nxt) {
            const int k0n = k0 + 64;
#pragma unroll
            for (int nt = 0; nt < 4; nt++) {
                int cc = min(k0n + nt * 16 + l16, NP - 1);
#pragma unroll
                for (int r = 0; r < 4; r++) biasr[nt * 4 + r] = browp[r][cc];
            }
#pragma unroll
            for (int r = 0; r < 4; r++)
                mr[r] = *(const uint2*)(mrowp[r] + (k0n >> 3));
        }

        // ---- O += P V  (same-wave Ps write->read; per-wave DS order) ----
        __builtin_amdgcn_s_setprio(1);
#pragma unroll
        for (int kc = 0; kc < 2; kc++) {
            short8 a = *(const short8*)&Ps[(16 * wave + l16) * LDP + kc * 32 + quad * 8];
#pragma unroll
            for (int nt = 0; nt < 4; nt++) {
                short8 bbf = *(const short8*)&Vs[(nt * 16 + l16) * LDP + kc * 32 + quad * 8];
                o_acc[nt] = __builtin_amdgcn_mfma_f32_16x16x32_bf16(a, bbf, o_acc[nt], 0, 0, 0);
            }
        }
        __builtin_amdgcn_s_setprio(0);

        // ---- stage prefetched K/V into LDS ----
        __syncthreads();
        if (nxt) {
            *(uint4*)&Ks[r0 * LDP + sg] = kr0;
            *(uint4*)&Ks[r1 * LDP + sg] = kr1;
            *(uint4*)&Vs[r0 * LDP + sg] = vr0;
            *(uint4*)&Vs[r1 * LDP + sg] = vr1;
        }
        __syncthreads();
    }

    // epilogue: reduce l across the 16-lane row group, normalize, store
#pragma unroll
    for (int r = 0; r < 4; r++) {
        float lt = l_lane[r];
        lt += __shfl_xor(lt, 1);
        lt += __shfl_xor(lt, 2);
        lt += __shfl_xor(lt, 4);
        lt += __shfl_xor(lt, 8);
        int q = q0 + 16 * wave + quad * 4 + r;
        if (q >= NP) continue;
        float inv = 1.f / lt;
#pragma unroll
        for (int nt = 0; nt < 4; nt++) {
            attnout[((size_t)b * NP + q) * ED + h * 64 + nt * 16 + l16] =
                __float2bfloat16(o_acc[nt][r] * inv);
        }
    }
}

// ---------------------------------------------------------------------------
// Kernel 3: output projection  out = attnout @ Wo^T + bo  (fp32 out)
// 64x128 tiles, grid (129, 4).
// ---------------------------------------------------------------------------
__global__ __launch_bounds__(256) void proj_gemm_kernel(
    const unsigned short* __restrict__ A,     // [8200,512] bf16 ws
    const unsigned short* __restrict__ wobf,  // [512,512] bf16
    const float* __restrict__ bo,
    float* __restrict__ out)
{
    __shared__ __align__(16) unsigned short As[64 * LDA];
    __shared__ __align__(16) unsigned short Bs[128 * LDA];

    const int t = threadIdx.x;
    const int wave = t >> 6, lane = t & 63;
    const int quad = lane >> 4, l16 = lane & 15;
    const int m0 = blockIdx.x * 64;
    const int n0 = blockIdx.y * 128;

    const int arow = t >> 2, aseg = (t & 3) * 8;
    const int ga = min(m0 + arow, NTOK - 1);
    const unsigned short* aptr = A + (size_t)ga * 512 + aseg;
    const int brw = t >> 1, bseg = (t & 1) * 16;
    const unsigned short* bptr = wobf + (size_t)(n0 + brw) * 512 + bseg;

    floatx4 acc[8];
#pragma unroll
    for (int i = 0; i < 8; i++) acc[i] = (floatx4){0.f, 0.f, 0.f, 0.f};

    uint4 ar = *(const uint4*)aptr;
    uint4 br0 = *(const uint4*)bptr;
    uint4 br1 = *(const uint4*)(bptr + 8);
    for (int s = 0; s < 16; s++) {
        __syncthreads();
        *(uint4*)&As[arow * LDA + aseg] = ar;
        *(uint4*)&Bs[brw * LDA + bseg] = br0;
        *(uint4*)&Bs[brw * LDA + bseg + 8] = br1;
        if (s < 15) {
            ar = *(const uint4*)(aptr + (s + 1) * 32);
            br0 = *(const uint4*)(bptr + (s + 1) * 32);
            br1 = *(const uint4*)(bptr + (s + 1) * 32 + 8);
        }
        __syncthreads();
        short8 a = *(const short8*)&As[(16 * wave + l16) * LDA + quad * 8];
#pragma unroll
        for (int nt = 0; nt < 8; nt++) {
            short8 bfr = *(const short8*)&Bs[(nt * 16 + l16) * LDA + quad * 8];
            acc[nt] = __builtin_amdgcn_mfma_f32_16x16x32_bf16(a, bfr, acc[nt], 0, 0, 0);
        }
    }

#pragma unroll
    for (int nt = 0; nt < 8; nt++) {
        int col = n0 + nt * 16 + l16;
        float bvv = bo[col];
#pragma unroll
        for (int r = 0; r < 4; r++) {
            int m = m0 + 16 * wave + quad * 4 + r;
            if (m >= NTOK) continue;
            out[(size_t)m * ED + col] = acc[nt][r] + bvv;
        }
    }
}

// ---------------------------------------------------------------------------
extern "C" void kernel_launch(void* const* d_in, const int* in_sizes, int n_in,
                              void* d_out, int out_size, void* d_ws, size_t ws_size,
                              hipStream_t stream) {
    (void)in_sizes; (void)n_in; (void)out_size; (void)ws_size;
    const float* x         = (const float*)d_in[0];
    const float* attn_bias = (const float*)d_in[1];
    const int*   pad_mask  = (const int*)d_in[2];
    const float* Wq = (const float*)d_in[3];
    const float* bq = (const float*)d_in[4];
    const float* Wk = (const float*)d_in[5];
    const float* bk = (const float*)d_in[6];
    const float* Wv = (const float*)d_in[7];
    const float* bv = (const float*)d_in[8];
    const float* Wo = (const float*)d_in[9];
    const float* bo = (const float*)d_in[10];
    float* out = (float*)d_out;

    // workspace layout (bytes); attnout reuses xbf (dead after qkv)
    char* ws = (char*)d_ws;
    const size_t XBF_BYTES = (size_t)NTOK * ED * 2;               // 8,396,800
    const size_t WBF_BYTES = (size_t)2048 * 512 * 2;              // 2,097,152
    const size_t QK_BYTES  = (size_t)BQ * NH * NP * HD * 2;       // 8,396,800
    const size_t VT_BYTES  = (size_t)BQ * NH * HD * VT_STRIDE * 2;// 8,912,896
    unsigned short* xbf    = (unsigned short*)(ws);
    unsigned short* wbf    = (unsigned short*)(ws + XBF_BYTES);
    __hip_bfloat16* qws    = (__hip_bfloat16*)(ws + XBF_BYTES + WBF_BYTES);
    __hip_bfloat16* kws    = (__hip_bfloat16*)(ws + XBF_BYTES + WBF_BYTES + QK_BYTES);
    __hip_bfloat16* vtws   = (__hip_bfloat16*)(ws + XBF_BYTES + WBF_BYTES + 2 * QK_BYTES);
    unsigned char*  maskbits = (unsigned char*)(ws + XBF_BYTES + WBF_BYTES + 2 * QK_BYTES + VT_BYTES);
    __hip_bfloat16* attnout = (__hip_bfloat16*)xbf;   // reuse

    cvt_kernel<<<4096, 256, 0, stream>>>(x, Wq, Wk, Wv, Wo, pad_mask, xbf, wbf, maskbits);
    qkv_gemm_kernel<<<dim3(136, 12), 256, 0, stream>>>(
        xbf, wbf, bq, bk, bv, qws, kws, vtws);
    attn_kernel<<<dim3(17, 64), 256, 0, stream>>>(
        qws, kws, vtws, attn_bias, maskbits, attnout);
    proj_gemm_kernel<<<dim3(129, 4), 256, 0, stream>>>(
        (const unsigned short*)attnout, wbf + (size_t)1536 * 512, bo, out);
}